// Round 10
// baseline (132.234 us; speedup 1.0000x reference)
//
#include <hip/hip_runtime.h>
#include <hip/hip_bf16.h>

// GridAttention: B=2, C=64, H=W=160, INTERVAL=8, HEADS=4, d=16
// Bp=128, h=w=20, N=400 (padded to 416). Token-major [bp][n][c], c=head*16+dd.

#define N_TOK 400
#define NP    416
#define BP    128

typedef short bf16x8 __attribute__((ext_vector_type(8)));
typedef float f32x16 __attribute__((ext_vector_type(16)));

__device__ inline ushort f2bf(float f) {
    __hip_bfloat16 h = __float2bfloat16(f);
    return *reinterpret_cast<ushort*>(&h);
}
__device__ inline float bf2f(ushort u) {
    union { uint i; float f; } v; v.i = (uint)u << 16; return v.f;
}
__device__ inline uint pk2(float a, float b) {
    return (uint)f2bf(a) | ((uint)f2bf(b) << 16);
}
__device__ inline bf16x8 ld16(const ushort* p) {
    union { uint4 q; bf16x8 v; } u;
    u.q = *reinterpret_cast<const uint4*>(p);
    return u.v;
}
__device__ inline float fast_exp2(float x) {
#if __has_builtin(__builtin_amdgcn_exp2f)
    return __builtin_amdgcn_exp2f(x);
#else
    return __expf(x * 0.6931471805599453f);
#endif
}
__device__ inline float fast_rcp(float x) {
#if __has_builtin(__builtin_amdgcn_rcpf)
    return __builtin_amdgcn_rcpf(x);
#else
    return 1.0f / x;
#endif
}

#define L2E 1.4426950408889634f
#define QK_PRESCALE 0.36067376022224085f   // 0.25 * log2(e), folded into Qb/Kb at conv

// ---------------- K0: fused weight prep + bias MLP ----------------
__global__ __launch_bounds__(256) void k_prep(
    const float* __restrict__ W1, const float* __restrict__ B1,
    const float* __restrict__ W2, const float* __restrict__ B2,
    const float* __restrict__ qkv_w, const float* __restrict__ qkv_b,
    const float* __restrict__ grid_w, const float* __restrict__ grid_b,
    const float* __restrict__ p1w, const float* __restrict__ p2w,
    float* __restrict__ biasF, ushort* __restrict__ Wc, float* __restrict__ Bc,
    ushort* __restrict__ Wp1, ushort* __restrict__ Wp2)
{
    int blk = blockIdx.x;
    if (blk < 2704) {
        int idx = blk * 256 + threadIdx.x;
        if (idx >= 692224) return;
        int r = idx & 15, lane = (idx >> 4) & 63;
        int tile = idx >> 10;
        int mt = tile % 13, rem = tile / 13, qt = rem % 13, h = rem / 13;
        int n = qt * 32 + (lane & 31);
        int m = mt * 32 + (r & 3) + 8 * (r >> 2) + 4 * (lane >> 5);
        float val = 0.0f;
        if (n < 400 && m < 400) {
            float r0 = (float)(n / 20 - m / 20) * (1.0f / 19.0f);
            float r1 = (float)(n % 20 - m % 20) * (1.0f / 19.0f);
            float o = B2[h];
#pragma unroll
            for (int k = 0; k < 16; ++k) {
                float hh = r0 * W1[k] + r1 * W1[16 + k] + B1[k];
                hh = fmaxf(hh, 0.0f);
                o += hh * W2[k * 4 + h];
            }
            val = o * L2E;   // exp2 domain; QK scale carried by Qb/Kb prescale
        }
        biasF[idx] = val;
    } else {
        int t = (blk - 2704) * 256 + threadIdx.x;
        if (t < 16384) {
            int oc = t >> 6, k = t & 63;
            float v = (oc < 192) ? qkv_w[oc * 64 + k] : grid_w[(oc - 192) * 64 + k];
            Wc[t] = f2bf(v);
        } else if (t < 16384 + 4096) {
            Wp1[t - 16384] = f2bf(p1w[t - 16384]);
        } else if (t < 16384 + 8192) {
            Wp2[t - 16384 - 4096] = f2bf(p2w[t - 16384 - 4096]);
        } else if (t < 16384 + 8192 + 256) {
            int oc = t - 16384 - 8192;
            Bc[oc] = (oc < 192) ? qkv_b[oc] : grid_b[oc - 192];
        }
    }
}

// ---------------- K2: fused qkv+grid conv1x1 as MFMA GEMM, shuffle on write ----------------
__global__ __launch_bounds__(256) void k_conv(
    const float* __restrict__ x, const ushort* __restrict__ Wc,
    const float* __restrict__ Bc,
    ushort* __restrict__ Qb, ushort* __restrict__ Kb,
    ushort* __restrict__ Vb, ushort* __restrict__ XGb)
{
    __shared__ __align__(16) ushort XL[32 * 64];
    int blk = blockIdx.x;                 // 1600 = 2*160*5
    int b = blk / 800, rem = blk % 800;
    int H0 = rem / 5, wt = rem % 5;
    int w0 = wt * 32;
    int tid = threadIdx.x;

    {
        int c = tid >> 2, q4 = tid & 3;
        const float* xr = x + ((size_t)(b * 64 + c) * 160 + H0) * 160 + w0 + q4 * 8;
        float4 f0 = *reinterpret_cast<const float4*>(xr);
        float4 f1 = *reinterpret_cast<const float4*>(xr + 4);
        char* base = reinterpret_cast<char*>(XL);
#pragma unroll
        for (int k = 0; k < 8; ++k) {
            float v = (k < 4) ? ((const float*)&f0)[k] : ((const float*)&f1)[k - 4];
            int p = q4 * 8 + k;
            int byt = p * 128 + ((2 * c) ^ ((p & 7) << 4));
            *reinterpret_cast<ushort*>(base + byt) = f2bf(v);
        }
    }

    int lane = tid & 63, w = tid >> 6;
    int l31 = lane & 31, hi = lane >> 5;

    bf16x8 wf[2][4];
#pragma unroll
    for (int nt = 0; nt < 2; ++nt)
#pragma unroll
        for (int kk = 0; kk < 4; ++kk)
            wf[nt][kk] = ld16(&Wc[(size_t)(w * 64 + nt * 32 + l31) * 64 + kk * 16 + hi * 8]);
    __syncthreads();

    f32x16 acc0 = 0.0f, acc1 = 0.0f;
    const char* base = reinterpret_cast<const char*>(XL);
#pragma unroll
    for (int kk = 0; kk < 4; ++kk) {
        int byt = l31 * 128 + (((kk * 32 + hi * 16)) ^ ((l31 & 7) << 4));
        bf16x8 xf;
        {
            union { uint4 q; bf16x8 v; } u;
            u.q = *reinterpret_cast<const uint4*>(base + byt);
            xf = u.v;
        }
        acc0 = __builtin_amdgcn_mfma_f32_32x32x16_bf16(wf[0][kk], xf, acc0, 0, 0, 0);
        acc1 = __builtin_amdgcn_mfma_f32_32x32x16_bf16(wf[1][kk], xf, acc1, 0, 0, 0);
    }

    int W0 = w0 + l31, ww = W0 >> 3, j = W0 & 7;
    int bp = b * 64 + (H0 & 7) * 8 + j;
    int n  = (H0 >> 3) * 20 + ww;
    ushort* outb = (w == 0) ? Qb : (w == 1) ? Kb : (w == 2) ? Vb : XGb;
    float mul = (w <= 1) ? QK_PRESCALE : 1.0f;
    ushort* dst = outb + ((size_t)bp * NP + n) * 64;
#pragma unroll
    for (int nt = 0; nt < 2; ++nt) {
        const f32x16& a = nt ? acc1 : acc0;
#pragma unroll
        for (int g = 0; g < 4; ++g) {
            int cc = nt * 32 + 8 * g + 4 * hi;
            int oc = w * 64 + cc;
            uint2 uu;
            uu.x = pk2((a[4 * g + 0] + Bc[oc + 0]) * mul, (a[4 * g + 1] + Bc[oc + 1]) * mul);
            uu.y = pk2((a[4 * g + 2] + Bc[oc + 2]) * mul, (a[4 * g + 3] + Bc[oc + 3]) * mul);
            *reinterpret_cast<uint2*>(dst + cc) = uu;
        }
    }
}

// ---------------- K3: MFMA attention, 4 independent q-chains per wave ----------------
// Grid 512 = (bp, head); 4 waves of 256 threads. Wave w owns qt {w, w+4, w+8, w+12(w==0)}.
// mt-outer loop: kf/vf loaded ONCE per mt, shared by all chains -> 4-way ILP on the
// bias-load/exp/pack chains. Bias via MFMA C-operand. PV B-cols 16..31 = 1.0 gives
// the softmax denominator for free in acc cols 16..31.
__global__ __launch_bounds__(256) void k_attn_mfma(
    const ushort* __restrict__ Qg, const ushort* __restrict__ Kg,
    const ushort* __restrict__ Vg, const float* __restrict__ biasF,
    ushort* __restrict__ O)
{
    __shared__ ushort Ks[NP * 16];    // [m][d]
    __shared__ ushort Vt[16 * 424];   // [d][m]
    int blk = blockIdx.x;
    int bp = blk >> 2, h = blk & 3;
    int tid = threadIdx.x;

    const ushort* Ksrc = Kg + (size_t)bp * NP * 64 + h * 16;
    for (int i = tid; i < NP * 2; i += 256) {
        int row = i >> 1, half = i & 1;
        *reinterpret_cast<uint4*>(&Ks[row * 16 + half * 8]) =
            *reinterpret_cast<const uint4*>(&Ksrc[(size_t)row * 64 + half * 8]);
    }
    const ushort* Vsrc = Vg + (size_t)bp * NP * 64 + h * 16;
    for (int i = tid; i < 800; i += 256) {
        int row = i >> 1, hf = i & 1;
        uint4 v = *reinterpret_cast<const uint4*>(&Vsrc[(size_t)row * 64 + hf * 8]);
        const ushort* pv = reinterpret_cast<const ushort*>(&v);
#pragma unroll
        for (int k = 0; k < 8; ++k)
            Vt[(hf * 8 + k) * 424 + row] = pv[k];
    }
    __syncthreads();

    int lane = tid & 63, w = tid >> 6;
    int l31 = lane & 31, hi = lane >> 5;

    const int qt0 = w, qt1 = w + 4, qt2 = w + 8;
    const int qt3 = (w == 0) ? 12 : w;          // chain 3 active only for wave 0
    const bool has3 = (w == 0);

    const size_t qrow = (size_t)bp * NP;
    bf16x8 qf0 = ld16(&Qg[(qrow + qt0 * 32 + l31) * 64 + h * 16 + hi * 8]);
    bf16x8 qf1 = ld16(&Qg[(qrow + qt1 * 32 + l31) * 64 + h * 16 + hi * 8]);
    bf16x8 qf2 = ld16(&Qg[(qrow + qt2 * 32 + l31) * 64 + h * 16 + hi * 8]);
    bf16x8 qf3 = ld16(&Qg[(qrow + qt3 * 32 + l31) * 64 + h * 16 + hi * 8]);

    const float* bbase = biasF + (size_t)h * 169 * 1024 + lane * 16;
    const f32x16* bf0 = reinterpret_cast<const f32x16*>(bbase + (size_t)qt0 * 13 * 1024);
    const f32x16* bf1 = reinterpret_cast<const f32x16*>(bbase + (size_t)qt1 * 13 * 1024);
    const f32x16* bf2 = reinterpret_cast<const f32x16*>(bbase + (size_t)qt2 * 13 * 1024);
    const f32x16* bf3 = reinterpret_cast<const f32x16*>(bbase + (size_t)qt3 * 13 * 1024);

    f32x16 a0 = 0.0f, a1 = 0.0f, a2 = 0.0f, a3 = 0.0f;

    const uint ONE2 = 0x3F803F80u;   // two bf16 1.0

#define QK_CHAIN(ACC, BFR, QF)                                                     \
    do {                                                                           \
        f32x16 cb_ = (BFR)[mt];                                                    \
        f32x16 sv_ = __builtin_amdgcn_mfma_f32_32x32x16_bf16(kf, QF, cb_, 0, 0, 0);\
        float p_[16];                                                              \
        _Pragma("unroll") for (int r_ = 0; r_ < 16; ++r_) p_[r_] = fast_exp2(sv_[r_]); \
        {                                                                          \
            uint c0 = pk2(p_[0], p_[1]), c1 = pk2(p_[2], p_[3]);                   \
            uint c2 = pk2(p_[4], p_[5]), c3 = pk2(p_[6], p_[7]);                   \
            asm("v_permlane32_swap_b32 %0, %1" : "+v"(c0), "+v"(c2));              \
            asm("v_permlane32_swap_b32 %0, %1" : "+v"(c1), "+v"(c3));              \
            union { uint u[4]; bf16x8 v; } A_;                                     \
            A_.u[0] = c0; A_.u[1] = c1; A_.u[2] = c2; A_.u[3] = c3;                \
            ACC = __builtin_amdgcn_mfma_f32_32x32x16_bf16(A_.v, vf0, ACC, 0, 0, 0);\
        }                                                                          \
        {                                                                          \
            uint c0 = pk2(p_[8], p_[9]),  c1 = pk2(p_[10], p_[11]);                \
            uint c2 = pk2(p_[12], p_[13]), c3 = pk2(p_[14], p_[15]);               \
            asm("v_permlane32_swap_b32 %0, %1" : "+v"(c0), "+v"(c2));              \
            asm("v_permlane32_swap_b32 %0, %1" : "+v"(c1), "+v"(c3));              \
            union { uint u[4]; bf16x8 v; } A_;                                     \
            A_.u[0] = c0; A_.u[1] = c1; A_.u[2] = c2; A_.u[3] = c3;                \
            ACC = __builtin_amdgcn_mfma_f32_32x32x16_bf16(A_.v, vf1, ACC, 0, 0, 0);\
        }                                                                          \
    } while (0)

    for (int mt = 0; mt < 12; ++mt) {
        const int mbase = mt * 32;
        bf16x8 kf = ld16(&Ks[(mbase + l31) * 16 + hi * 8]);
        bf16x8 vf0, vf1;
        if (l31 < 16) {
            vf0 = ld16(&Vt[l31 * 424 + mbase + hi * 8]);
            vf1 = ld16(&Vt[l31 * 424 + mbase + 16 + hi * 8]);
        } else {
            union { uint u[4]; bf16x8 v; } o;
            o.u[0] = o.u[1] = o.u[2] = o.u[3] = ONE2;
            vf0 = o.v; vf1 = o.v;
        }
        QK_CHAIN(a0, bf0, qf0);
        QK_CHAIN(a1, bf1, qf1);
        QK_CHAIN(a2, bf2, qf2);
        if (has3) QK_CHAIN(a3, bf3, qf3);
    }

    // tail mt = 12: valid m rows 384..399 only (regs 0..7 of S; PV chunk 0 only)
    {
        bf16x8 kf = ld16(&Ks[(384 + l31) * 16 + hi * 8]);
        bf16x8 vf0;
        if (l31 < 16) vf0 = ld16(&Vt[l31 * 424 + 384 + hi * 8]);
        else { union { uint u[4]; bf16x8 v; } o; o.u[0]=o.u[1]=o.u[2]=o.u[3]=ONE2; vf0 = o.v; }

#define QK_TAIL(ACC, BFR, QF)                                                      \
        do {                                                                       \
            f32x16 cb_ = (BFR)[12];                                                \
            f32x16 sv_ = __builtin_amdgcn_mfma_f32_32x32x16_bf16(kf, QF, cb_, 0, 0, 0); \
            float p_[8];                                                           \
            _Pragma("unroll") for (int r_ = 0; r_ < 8; ++r_) p_[r_] = fast_exp2(sv_[r_]); \
            uint c0 = pk2(p_[0], p_[1]), c1 = pk2(p_[2], p_[3]);                   \
            uint c2 = pk2(p_[4], p_[5]), c3 = pk2(p_[6], p_[7]);                   \
            asm("v_permlane32_swap_b32 %0, %1" : "+v"(c0), "+v"(c2));              \
            asm("v_permlane32_swap_b32 %0, %1" : "+v"(c1), "+v"(c3));              \
            union { uint u[4]; bf16x8 v; } A_;                                     \
            A_.u[0] = c0; A_.u[1] = c1; A_.u[2] = c2; A_.u[3] = c3;                \
            ACC = __builtin_amdgcn_mfma_f32_32x32x16_bf16(A_.v, vf0, ACC, 0, 0, 0);\
        } while (0)

        QK_TAIL(a0, bf0, qf0);
        QK_TAIL(a1, bf1, qf1);
        QK_TAIL(a2, bf2, qf2);
        if (has3) QK_TAIL(a3, bf3, qf3);
    }

    // normalize + store: denominator for row r sits in lane (lane|16), same register.
#define STORE_CHAIN(ACC, QT)                                                       \
    do {                                                                           \
        int qbase_ = (QT) * 32;                                                    \
        _Pragma("unroll") for (int r_ = 0; r_ < 16; ++r_) {                        \
            int moff_ = (r_ & 3) + 8 * (r_ >> 2) + 4 * hi;                         \
            int q_ = qbase_ + moff_;                                               \
            float s_ = __shfl(ACC[r_], lane | 16);                                 \
            if (l31 < 16 && q_ < N_TOK)                                            \
                O[((size_t)bp * 400 + q_) * 64 + h * 16 + l31] =                   \
                    f2bf(ACC[r_] * fast_rcp(s_));                                  \
        }                                                                          \
    } while (0)

    STORE_CHAIN(a0, qt0);
    STORE_CHAIN(a1, qt1);
    STORE_CHAIN(a2, qt2);
    if (has3) STORE_CHAIN(a3, qt3);

#undef QK_CHAIN
#undef QK_TAIL
#undef STORE_CHAIN
}

// ---------------- K4: 64x64 proj as MFMA GEMM (bf16 in, bf16 out) ----------------
// MODE 0: out NP-padded token-major (for attn V input). MODE 1: out contiguous token-major.
template<int MODE>
__global__ __launch_bounds__(256) void k_proj(
    const ushort* __restrict__ In, const ushort* __restrict__ Wp,
    const float* __restrict__ Bv, ushort* __restrict__ Out)
{
    __shared__ __align__(16) ushort XL[128 * 64];
    size_t t0 = (size_t)blockIdx.x * 128;
    int tid = threadIdx.x;

    char* basec = reinterpret_cast<char*>(XL);
#pragma unroll
    for (int it = 0; it < 4; ++it) {
        int idx = tid + it * 256;
        int p = idx >> 3, c8 = idx & 7;
        uint4 v = *reinterpret_cast<const uint4*>(In + (t0 + p) * 64 + c8 * 8);
        int byt = p * 128 + ((c8 * 16) ^ ((p & 7) << 4));
        *reinterpret_cast<uint4*>(basec + byt) = v;
    }

    int lane = tid & 63, w = tid >> 6;
    int l31 = lane & 31, hi = lane >> 5;

    bf16x8 wf[2][4];
#pragma unroll
    for (int nt = 0; nt < 2; ++nt)
#pragma unroll
        for (int kk = 0; kk < 4; ++kk)
            wf[nt][kk] = ld16(&Wp[(size_t)(nt * 32 + l31) * 64 + kk * 16 + hi * 8]);
    __syncthreads();

    int prow = w * 32 + l31;
    f32x16 acc0 = 0.0f, acc1 = 0.0f;
#pragma unroll
    for (int kk = 0; kk < 4; ++kk) {
        int byt = prow * 128 + (((kk * 32 + hi * 16)) ^ ((prow & 7) << 4));
        union { uint4 q; bf16x8 v; } u;
        u.q = *reinterpret_cast<const uint4*>(basec + byt);
        acc0 = __builtin_amdgcn_mfma_f32_32x32x16_bf16(wf[0][kk], u.v, acc0, 0, 0, 0);
        acc1 = __builtin_amdgcn_mfma_f32_32x32x16_bf16(wf[1][kk], u.v, acc1, 0, 0, 0);
    }

    size_t t = t0 + prow;
    ushort* dst;
    if (MODE == 0) {
        int bp = (int)(t / 400), n = (int)(t % 400);
        dst = Out + ((size_t)bp * NP + n) * 64;
    } else {
        dst = Out + t * 64;
    }
#pragma unroll
    for (int nt = 0; nt < 2; ++nt) {
        const f32x16& a = nt ? acc1 : acc0;
#pragma unroll
        for (int g = 0; g < 4; ++g) {
            int cc = nt * 32 + 8 * g + 4 * hi;
            uint2 uu;
            uu.x = pk2(a[4 * g + 0] + Bv[cc + 0], a[4 * g + 1] + Bv[cc + 1]);
            uu.y = pk2(a[4 * g + 2] + Bv[cc + 2], a[4 * g + 3] + Bv[cc + 3]);
            *reinterpret_cast<uint2*>(dst + cc) = uu;
        }
    }
}

// ---------------- K5: grid_unshuffle (token-major bf16 -> [B][C][160][160] fp32) ----------------
__global__ __launch_bounds__(256) void k_unshuffle(
    const ushort* __restrict__ In, float* __restrict__ out)
{
    __shared__ __align__(16) ushort il[160 * 64];
    int blk = blockIdx.x;
    int b = blk / 160, rem = blk % 160, iI = rem / 20, hh = rem % 20;
    int tid = threadIdx.x;

    for (int idx = tid; idx < 1280; idx += 256) {
        int j = idx / 160, r2 = idx % 160, ww = r2 / 8, c8 = r2 % 8;
        int bp = b * 64 + iI * 8 + j;
        int n  = hh * 20 + ww;
        uint4 v = reinterpret_cast<const uint4*>(In + ((size_t)bp * 400 + n) * 64)[c8];
        reinterpret_cast<uint4*>(&il[(ww * 8 + j) * 64])[c8] = v;
    }
    __syncthreads();

    int c = tid >> 2, q = tid & 3;
    int H0 = hh * 8 + iI;
    float* og = out + ((size_t)(b * 64 + c) * 160 + H0) * 160;
#pragma unroll
    for (int k = 0; k < 10; ++k) {
        int f = q + 4 * k;
        float4 v;
        v.x = bf2f(il[(4 * f + 0) * 64 + c]);
        v.y = bf2f(il[(4 * f + 1) * 64 + c]);
        v.z = bf2f(il[(4 * f + 2) * 64 + c]);
        v.w = bf2f(il[(4 * f + 3) * 64 + c]);
        reinterpret_cast<float4*>(og)[f] = v;
    }
}

extern "C" void kernel_launch(void* const* d_in, const int* in_sizes, int n_in,
                              void* d_out, int out_size, void* d_ws, size_t ws_size,
                              hipStream_t stream)
{
    const float* x      = (const float*)d_in[0];
    const float* qkv_w  = (const float*)d_in[1];
    const float* qkv_b  = (const float*)d_in[2];
    const float* grid_w = (const float*)d_in[3];
    const float* grid_b = (const float*)d_in[4];
    const float* pw1    = (const float*)d_in[5];
    const float* pb1    = (const float*)d_in[6];
    const float* pw2    = (const float*)d_in[7];
    const float* pb2    = (const float*)d_in[8];
    const float* p1w    = (const float*)d_in[9];
    const float* p1b    = (const float*)d_in[10];
    const float* p2w    = (const float*)d_in[11];
    const float* p2b    = (const float*)d_in[12];

    // workspace layout (byte offsets, all 16B-aligned)
    char* W = (char*)d_ws;
    float*  biasF = (float*)(W + 0);             // 692224*4 = 2,768,896
    ushort* Wc    = (ushort*)(W + 2768896);      // 32,768
    ushort* Wp1   = (ushort*)(W + 2801664);      //  8,192
    ushort* Wp2   = (ushort*)(W + 2809856);      //  8,192
    float*  Bc    = (float*) (W + 2818048);      //  1,024
    const size_t BASE2 = 2819072;
    const size_t BB = (size_t)BP * NP * 64 * 2;  // 6,815,744 per bf16 NP buffer
    ushort* Qb = (ushort*)(W + BASE2);
    ushort* Kb = (ushort*)(W + BASE2 + 1 * BB);
    ushort* Vb = (ushort*)(W + BASE2 + 2 * BB);
    ushort* XG = (ushort*)(W + BASE2 + 3 * BB);
    ushort* P1 = (ushort*)(W + BASE2 + 4 * BB);
    const size_t OB = (size_t)BP * 400 * 64 * 2; // 6,553,600 per bf16 contiguous buffer
    ushort* O1 = (ushort*)(W + BASE2 + 5 * BB);
    ushort* O2 = (ushort*)(W + BASE2 + 5 * BB + OB);
    ushort* OFb = O1;   // proj2 output reuses O1 (dead after proj1)
    float*  out = (float*)d_out;

    k_prep<<<2801, 256, 0, stream>>>(pw1, pb1, pw2, pb2, qkv_w, qkv_b, grid_w, grid_b,
                                     p1w, p2w, biasF, Wc, Bc, Wp1, Wp2);
    k_conv<<<1600, 256, 0, stream>>>(x, Wc, Bc, Qb, Kb, Vb, XG);
    // attn1: q=XG, k=Kb(prescaled), v=Vb -> O1; proj1 -> P1 (bf16, NP-padded)
    k_attn_mfma<<<512, 256, 0, stream>>>(XG, Kb, Vb, biasF, O1);
    k_proj<0><<<400, 256, 0, stream>>>(O1, Wp1, p1b, P1);
    // attn2: q=Qb(prescaled), k=XG, v=P1 -> O2; proj2 -> OFb (bf16, overlays O1)
    k_attn_mfma<<<512, 256, 0, stream>>>(Qb, XG, P1, biasF, O2);
    k_proj<1><<<400, 256, 0, stream>>>(O2, Wp2, p2b, OFb);
    k_unshuffle<<<320, 256, 0, stream>>>(OFb, out);
}

// Round 11
// 114.815 us; speedup vs baseline: 1.1517x; 1.1517x over previous
//
#include <hip/hip_runtime.h>
#include <hip/hip_bf16.h>

// GridAttention: B=2, C=64, H=W=160, INTERVAL=8, HEADS=4, d=16
// Bp=128, h=w=20, N=400 (padded to 416). Token-major [bp][n][c], c=head*16+dd.

#define N_TOK 400
#define NP    416
#define BP    128

typedef short bf16x8 __attribute__((ext_vector_type(8)));
typedef float f32x16 __attribute__((ext_vector_type(16)));

__device__ inline ushort f2bf(float f) {
    __hip_bfloat16 h = __float2bfloat16(f);
    return *reinterpret_cast<ushort*>(&h);
}
__device__ inline float bf2f(ushort u) {
    union { uint i; float f; } v; v.i = (uint)u << 16; return v.f;
}
__device__ inline uint pk2(float a, float b) {
    return (uint)f2bf(a) | ((uint)f2bf(b) << 16);
}
__device__ inline bf16x8 ld16(const ushort* p) {
    union { uint4 q; bf16x8 v; } u;
    u.q = *reinterpret_cast<const uint4*>(p);
    return u.v;
}
__device__ inline float fast_exp2(float x) {
#if __has_builtin(__builtin_amdgcn_exp2f)
    return __builtin_amdgcn_exp2f(x);
#else
    return __expf(x * 0.6931471805599453f);
#endif
}
__device__ inline float fast_rcp(float x) {
#if __has_builtin(__builtin_amdgcn_rcpf)
    return __builtin_amdgcn_rcpf(x);
#else
    return 1.0f / x;
#endif
}

#define L2E 1.4426950408889634f
#define QK_PRESCALE 0.36067376022224085f   // 0.25 * log2(e), folded into Qb/Kb at conv

// ---------------- K0: fused weight prep + bias MLP ----------------
// blocks [0,2704): biasF[h][qt][mt][lane][r] fp32, value = log2(e)*bias (fragment-major,
//   n = qt*32+(lane&31), m = mt*32+(r&3)+8*(r>>2)+4*(lane>>5)); 692224 floats.
// blocks [2704,2801): bf16 weight conversion + bias concat.
__global__ __launch_bounds__(256) void k_prep(
    const float* __restrict__ W1, const float* __restrict__ B1,
    const float* __restrict__ W2, const float* __restrict__ B2,
    const float* __restrict__ qkv_w, const float* __restrict__ qkv_b,
    const float* __restrict__ grid_w, const float* __restrict__ grid_b,
    const float* __restrict__ p1w, const float* __restrict__ p2w,
    float* __restrict__ biasF, ushort* __restrict__ Wc, float* __restrict__ Bc,
    ushort* __restrict__ Wp1, ushort* __restrict__ Wp2)
{
    int blk = blockIdx.x;
    if (blk < 2704) {
        int idx = blk * 256 + threadIdx.x;
        if (idx >= 692224) return;
        int r = idx & 15, lane = (idx >> 4) & 63;
        int tile = idx >> 10;
        int mt = tile % 13, rem = tile / 13, qt = rem % 13, h = rem / 13;
        int n = qt * 32 + (lane & 31);
        int m = mt * 32 + (r & 3) + 8 * (r >> 2) + 4 * (lane >> 5);
        float val = 0.0f;
        if (n < 400 && m < 400) {
            float r0 = (float)(n / 20 - m / 20) * (1.0f / 19.0f);
            float r1 = (float)(n % 20 - m % 20) * (1.0f / 19.0f);
            float o = B2[h];
#pragma unroll
            for (int k = 0; k < 16; ++k) {
                float hh = r0 * W1[k] + r1 * W1[16 + k] + B1[k];
                hh = fmaxf(hh, 0.0f);
                o += hh * W2[k * 4 + h];
            }
            val = o * L2E;   // exp2 domain; QK scale carried by Qb/Kb prescale
        }
        biasF[idx] = val;
    } else {
        int t = (blk - 2704) * 256 + threadIdx.x;
        if (t < 16384) {
            int oc = t >> 6, k = t & 63;
            float v = (oc < 192) ? qkv_w[oc * 64 + k] : grid_w[(oc - 192) * 64 + k];
            Wc[t] = f2bf(v);
        } else if (t < 16384 + 4096) {
            Wp1[t - 16384] = f2bf(p1w[t - 16384]);
        } else if (t < 16384 + 8192) {
            Wp2[t - 16384 - 4096] = f2bf(p2w[t - 16384 - 4096]);
        } else if (t < 16384 + 8192 + 256) {
            int oc = t - 16384 - 8192;
            Bc[oc] = (oc < 192) ? qkv_b[oc] : grid_b[oc - 192];
        }
    }
}

// ---------------- K2: fused qkv+grid conv1x1 as MFMA GEMM, shuffle on write ----------------
// Wave 0 -> Qb, 1 -> Kb (both pre-scaled by 0.25*log2e), 2 -> Vb, 3 -> XGb.
__global__ __launch_bounds__(256) void k_conv(
    const float* __restrict__ x, const ushort* __restrict__ Wc,
    const float* __restrict__ Bc,
    ushort* __restrict__ Qb, ushort* __restrict__ Kb,
    ushort* __restrict__ Vb, ushort* __restrict__ XGb)
{
    __shared__ __align__(16) ushort XL[32 * 64];
    int blk = blockIdx.x;                 // 1600 = 2*160*5
    int b = blk / 800, rem = blk % 800;
    int H0 = rem / 5, wt = rem % 5;
    int w0 = wt * 32;
    int tid = threadIdx.x;

    {
        int c = tid >> 2, q4 = tid & 3;
        const float* xr = x + ((size_t)(b * 64 + c) * 160 + H0) * 160 + w0 + q4 * 8;
        float4 f0 = *reinterpret_cast<const float4*>(xr);
        float4 f1 = *reinterpret_cast<const float4*>(xr + 4);
        char* base = reinterpret_cast<char*>(XL);
#pragma unroll
        for (int k = 0; k < 8; ++k) {
            float v = (k < 4) ? ((const float*)&f0)[k] : ((const float*)&f1)[k - 4];
            int p = q4 * 8 + k;
            int byt = p * 128 + ((2 * c) ^ ((p & 7) << 4));
            *reinterpret_cast<ushort*>(base + byt) = f2bf(v);
        }
    }

    int lane = tid & 63, w = tid >> 6;
    int l31 = lane & 31, hi = lane >> 5;

    bf16x8 wf[2][4];
#pragma unroll
    for (int nt = 0; nt < 2; ++nt)
#pragma unroll
        for (int kk = 0; kk < 4; ++kk)
            wf[nt][kk] = ld16(&Wc[(size_t)(w * 64 + nt * 32 + l31) * 64 + kk * 16 + hi * 8]);
    __syncthreads();

    f32x16 acc0 = 0.0f, acc1 = 0.0f;
    const char* base = reinterpret_cast<const char*>(XL);
#pragma unroll
    for (int kk = 0; kk < 4; ++kk) {
        int byt = l31 * 128 + (((kk * 32 + hi * 16)) ^ ((l31 & 7) << 4));
        bf16x8 xf;
        {
            union { uint4 q; bf16x8 v; } u;
            u.q = *reinterpret_cast<const uint4*>(base + byt);
            xf = u.v;
        }
        acc0 = __builtin_amdgcn_mfma_f32_32x32x16_bf16(wf[0][kk], xf, acc0, 0, 0, 0);
        acc1 = __builtin_amdgcn_mfma_f32_32x32x16_bf16(wf[1][kk], xf, acc1, 0, 0, 0);
    }

    int W0 = w0 + l31, ww = W0 >> 3, j = W0 & 7;
    int bp = b * 64 + (H0 & 7) * 8 + j;
    int n  = (H0 >> 3) * 20 + ww;
    ushort* outb = (w == 0) ? Qb : (w == 1) ? Kb : (w == 2) ? Vb : XGb;
    float mul = (w <= 1) ? QK_PRESCALE : 1.0f;
    ushort* dst = outb + ((size_t)bp * NP + n) * 64;
#pragma unroll
    for (int nt = 0; nt < 2; ++nt) {
        const f32x16& a = nt ? acc1 : acc0;
#pragma unroll
        for (int g = 0; g < 4; ++g) {
            int cc = nt * 32 + 8 * g + 4 * hi;
            int oc = w * 64 + cc;
            uint2 uu;
            uu.x = pk2((a[4 * g + 0] + Bc[oc + 0]) * mul, (a[4 * g + 1] + Bc[oc + 1]) * mul);
            uu.y = pk2((a[4 * g + 2] + Bc[oc + 2]) * mul, (a[4 * g + 3] + Bc[oc + 3]) * mul);
            *reinterpret_cast<uint2*>(dst + cc) = uu;
        }
    }
}

// ---------------- K3: MFMA attention (r8 structure + f32x16 bias + setprio) ----------------
// Grid 512 = (bp, head); 8 waves. Wave w owns q-tiles {w, w+8} (13 total).
// Bias via MFMA C-operand, fragment-major f32x16 loads, double-buffer prefetched.
// PV B-cols 16..31 = 1.0 -> softmax denominator accumulates in acc cols 16..31 free.
__global__ __launch_bounds__(512, 4) void k_attn_mfma(
    const ushort* __restrict__ Qg, const ushort* __restrict__ Kg,
    const ushort* __restrict__ Vg, const float* __restrict__ biasF,
    ushort* __restrict__ O)
{
    __shared__ ushort Ks[NP * 16];    // [m][d]
    __shared__ ushort Vt[16 * 424];   // [d][m]
    int blk = blockIdx.x;
    int bp = blk >> 2, h = blk & 3;
    int tid = threadIdx.x;

    const ushort* Ksrc = Kg + (size_t)bp * NP * 64 + h * 16;
#pragma unroll
    for (int it = 0; it < 2; ++it) {
        int i = tid + it * 512;
        if (i < NP * 2) {
            int row = i >> 1, half = i & 1;
            *reinterpret_cast<uint4*>(&Ks[row * 16 + half * 8]) =
                *reinterpret_cast<const uint4*>(&Ksrc[(size_t)row * 64 + half * 8]);
        }
    }
    const ushort* Vsrc = Vg + (size_t)bp * NP * 64 + h * 16;
#pragma unroll
    for (int it = 0; it < 2; ++it) {
        int i = tid + it * 512;
        if (i < 800) {
            int row = i >> 1, hf = i & 1;
            uint4 v = *reinterpret_cast<const uint4*>(&Vsrc[(size_t)row * 64 + hf * 8]);
            const ushort* pv = reinterpret_cast<const ushort*>(&v);
#pragma unroll
            for (int k = 0; k < 8; ++k)
                Vt[(hf * 8 + k) * 424 + row] = pv[k];
        }
    }
    __syncthreads();

    int lane = tid & 63, w = tid >> 6;
    int l31 = lane & 31, hi = lane >> 5;
    const uint ONE2 = 0x3F803F80u;   // two bf16 1.0

    for (int qt = w; qt < 13; qt += 8) {
        int qbase = qt * 32;
        bf16x8 qf = ld16(&Qg[((size_t)bp * NP + qbase + l31) * 64 + h * 16 + hi * 8]);
        f32x16 acc = 0.0f;
        const f32x16* bfr = reinterpret_cast<const f32x16*>(
            biasF + ((size_t)(h * 169 + qt * 13)) * 1024 + lane * 16);

        f32x16 cb = bfr[0];

#pragma unroll
        for (int mt = 0; mt < 13; ++mt) {
            const int mbase = mt * 32;
            f32x16 nb;
            if (mt < 12) nb = bfr[mt + 1];   // prefetch next tile's bias (prio 0)

            __builtin_amdgcn_s_setprio(1);
            bf16x8 kf = ld16(&Ks[(mbase + l31) * 16 + hi * 8]);
            f32x16 sv = __builtin_amdgcn_mfma_f32_32x32x16_bf16(kf, qf, cb, 0, 0, 0);

            const int nv = (mt == 12) ? 8 : 16;
            float p[16];
#pragma unroll
            for (int r = 0; r < 16; ++r)
                if (r < nv) p[r] = fast_exp2(sv[r]);

            // B-operand: cols <16 = V, cols >=16 = 1.0 (denominator column)
            {
                uint c4 = pk2(p[0], p[1]), c5 = pk2(p[2], p[3]);
                uint c6 = pk2(p[4], p[5]), c7 = pk2(p[6], p[7]);
                asm("v_permlane32_swap_b32 %0, %1" : "+v"(c4), "+v"(c6));
                asm("v_permlane32_swap_b32 %0, %1" : "+v"(c5), "+v"(c7));
                union { uint u[4]; bf16x8 v; } A;
                A.u[0] = c4; A.u[1] = c5; A.u[2] = c6; A.u[3] = c7;
                bf16x8 vf;
                if (l31 < 16) vf = ld16(&Vt[l31 * 424 + mbase + hi * 8]);
                else { union { uint u[4]; bf16x8 v; } o; o.u[0]=o.u[1]=o.u[2]=o.u[3]=ONE2; vf = o.v; }
                acc = __builtin_amdgcn_mfma_f32_32x32x16_bf16(A.v, vf, acc, 0, 0, 0);
            }
            if (mt < 12) {
                uint c4 = pk2(p[8], p[9]),  c5 = pk2(p[10], p[11]);
                uint c6 = pk2(p[12], p[13]), c7 = pk2(p[14], p[15]);
                asm("v_permlane32_swap_b32 %0, %1" : "+v"(c4), "+v"(c6));
                asm("v_permlane32_swap_b32 %0, %1" : "+v"(c5), "+v"(c7));
                union { uint u[4]; bf16x8 v; } A;
                A.u[0] = c4; A.u[1] = c5; A.u[2] = c6; A.u[3] = c7;
                bf16x8 vf;
                if (l31 < 16) vf = ld16(&Vt[l31 * 424 + mbase + 16 + hi * 8]);
                else { union { uint u[4]; bf16x8 v; } o; o.u[0]=o.u[1]=o.u[2]=o.u[3]=ONE2; vf = o.v; }
                acc = __builtin_amdgcn_mfma_f32_32x32x16_bf16(A.v, vf, acc, 0, 0, 0);
            }
            __builtin_amdgcn_s_setprio(0);
            cb = nb;
        }

        // normalize + store: denominator for row r sits in lane (lane|16), same register.
#pragma unroll
        for (int r = 0; r < 16; ++r) {
            int moff = (r & 3) + 8 * (r >> 2) + 4 * hi;
            int q = qbase + moff;
            float s = __shfl(acc[r], lane | 16);
            if (l31 < 16 && q < N_TOK)
                O[((size_t)bp * 400 + q) * 64 + h * 16 + l31] = f2bf(acc[r] * fast_rcp(s));
        }
    }
}

// ---------------- K4: 64x64 proj as MFMA GEMM (bf16 in, bf16 out) ----------------
// MODE 0: out NP-padded token-major (for attn V input). MODE 1: out contiguous token-major.
template<int MODE>
__global__ __launch_bounds__(256) void k_proj(
    const ushort* __restrict__ In, const ushort* __restrict__ Wp,
    const float* __restrict__ Bv, ushort* __restrict__ Out)
{
    __shared__ __align__(16) ushort XL[128 * 64];
    size_t t0 = (size_t)blockIdx.x * 128;
    int tid = threadIdx.x;

    char* basec = reinterpret_cast<char*>(XL);
#pragma unroll
    for (int it = 0; it < 4; ++it) {
        int idx = tid + it * 256;
        int p = idx >> 3, c8 = idx & 7;
        uint4 v = *reinterpret_cast<const uint4*>(In + (t0 + p) * 64 + c8 * 8);
        int byt = p * 128 + ((c8 * 16) ^ ((p & 7) << 4));
        *reinterpret_cast<uint4*>(basec + byt) = v;
    }

    int lane = tid & 63, w = tid >> 6;
    int l31 = lane & 31, hi = lane >> 5;

    bf16x8 wf[2][4];
#pragma unroll
    for (int nt = 0; nt < 2; ++nt)
#pragma unroll
        for (int kk = 0; kk < 4; ++kk)
            wf[nt][kk] = ld16(&Wp[(size_t)(nt * 32 + l31) * 64 + kk * 16 + hi * 8]);
    __syncthreads();

    int prow = w * 32 + l31;
    f32x16 acc0 = 0.0f, acc1 = 0.0f;
#pragma unroll
    for (int kk = 0; kk < 4; ++kk) {
        int byt = prow * 128 + (((kk * 32 + hi * 16)) ^ ((prow & 7) << 4));
        union { uint4 q; bf16x8 v; } u;
        u.q = *reinterpret_cast<const uint4*>(basec + byt);
        acc0 = __builtin_amdgcn_mfma_f32_32x32x16_bf16(wf[0][kk], u.v, acc0, 0, 0, 0);
        acc1 = __builtin_amdgcn_mfma_f32_32x32x16_bf16(wf[1][kk], u.v, acc1, 0, 0, 0);
    }

    size_t t = t0 + prow;
    ushort* dst;
    if (MODE == 0) {
        int bp = (int)(t / 400), n = (int)(t % 400);
        dst = Out + ((size_t)bp * NP + n) * 64;
    } else {
        dst = Out + t * 64;
    }
#pragma unroll
    for (int nt = 0; nt < 2; ++nt) {
        const f32x16& a = nt ? acc1 : acc0;
#pragma unroll
        for (int g = 0; g < 4; ++g) {
            int cc = nt * 32 + 8 * g + 4 * hi;
            uint2 uu;
            uu.x = pk2(a[4 * g + 0] + Bv[cc + 0], a[4 * g + 1] + Bv[cc + 1]);
            uu.y = pk2(a[4 * g + 2] + Bv[cc + 2], a[4 * g + 3] + Bv[cc + 3]);
            *reinterpret_cast<uint2*>(dst + cc) = uu;
        }
    }
}

// ---------------- K5: grid_unshuffle (token-major bf16 -> [B][C][160][160] fp32) ----------------
__global__ __launch_bounds__(256) void k_unshuffle(
    const ushort* __restrict__ In, float* __restrict__ out)
{
    __shared__ __align__(16) ushort il[160 * 64];
    int blk = blockIdx.x;
    int b = blk / 160, rem = blk % 160, iI = rem / 20, hh = rem % 20;
    int tid = threadIdx.x;

    for (int idx = tid; idx < 1280; idx += 256) {
        int j = idx / 160, r2 = idx % 160, ww = r2 / 8, c8 = r2 % 8;
        int bp = b * 64 + iI * 8 + j;
        int n  = hh * 20 + ww;
        uint4 v = reinterpret_cast<const uint4*>(In + ((size_t)bp * 400 + n) * 64)[c8];
        reinterpret_cast<uint4*>(&il[(ww * 8 + j) * 64])[c8] = v;
    }
    __syncthreads();

    int c = tid >> 2, q = tid & 3;
    int H0 = hh * 8 + iI;
    float* og = out + ((size_t)(b * 64 + c) * 160 + H0) * 160;
#pragma unroll
    for (int k = 0; k < 10; ++k) {
        int f = q + 4 * k;
        float4 v;
        v.x = bf2f(il[(4 * f + 0) * 64 + c]);
        v.y = bf2f(il[(4 * f + 1) * 64 + c]);
        v.z = bf2f(il[(4 * f + 2) * 64 + c]);
        v.w = bf2f(il[(4 * f + 3) * 64 + c]);
        reinterpret_cast<float4*>(og)[f] = v;
    }
}

extern "C" void kernel_launch(void* const* d_in, const int* in_sizes, int n_in,
                              void* d_out, int out_size, void* d_ws, size_t ws_size,
                              hipStream_t stream)
{
    const float* x      = (const float*)d_in[0];
    const float* qkv_w  = (const float*)d_in[1];
    const float* qkv_b  = (const float*)d_in[2];
    const float* grid_w = (const float*)d_in[3];
    const float* grid_b = (const float*)d_in[4];
    const float* pw1    = (const float*)d_in[5];
    const float* pb1    = (const float*)d_in[6];
    const float* pw2    = (const float*)d_in[7];
    const float* pb2    = (const float*)d_in[8];
    const float* p1w    = (const float*)d_in[9];
    const float* p1b    = (const float*)d_in[10];
    const float* p2w    = (const float*)d_in[11];
    const float* p2b    = (const float*)d_in[12];

    // workspace layout (byte offsets, all 16B-aligned)
    char* W = (char*)d_ws;
    float*  biasF = (float*)(W + 0);             // 692224*4 = 2,768,896
    ushort* Wc    = (ushort*)(W + 2768896);      // 32,768
    ushort* Wp1   = (ushort*)(W + 2801664);      //  8,192
    ushort* Wp2   = (ushort*)(W + 2809856);      //  8,192
    float*  Bc    = (float*) (W + 2818048);      //  1,024
    const size_t BASE2 = 2819072;
    const size_t BB = (size_t)BP * NP * 64 * 2;  // 6,815,744 per bf16 NP buffer
    ushort* Qb = (ushort*)(W + BASE2);
    ushort* Kb = (ushort*)(W + BASE2 + 1 * BB);
    ushort* Vb = (ushort*)(W + BASE2 + 2 * BB);
    ushort* XG = (ushort*)(W + BASE2 + 3 * BB);
    ushort* P1 = (ushort*)(W + BASE2 + 4 * BB);
    const size_t OB = (size_t)BP * 400 * 64 * 2; // 6,553,600 per bf16 contiguous buffer
    ushort* O1 = (ushort*)(W + BASE2 + 5 * BB);
    ushort* O2 = (ushort*)(W + BASE2 + 5 * BB + OB);
    ushort* OFb = O1;   // proj2 output reuses O1 (dead after proj1)
    float*  out = (float*)d_out;

    k_prep<<<2801, 256, 0, stream>>>(pw1, pb1, pw2, pb2, qkv_w, qkv_b, grid_w, grid_b,
                                     p1w, p2w, biasF, Wc, Bc, Wp1, Wp2);
    k_conv<<<1600, 256, 0, stream>>>(x, Wc, Bc, Qb, Kb, Vb, XG);
    // attn1: q=XG, k=Kb(prescaled), v=Vb -> O1; proj1 -> P1 (bf16, NP-padded)
    k_attn_mfma<<<512, 512, 0, stream>>>(XG, Kb, Vb, biasF, O1);
    k_proj<0><<<400, 256, 0, stream>>>(O1, Wp1, p1b, P1);
    // attn2: q=Qb(prescaled), k=XG, v=P1 -> O2; proj2 -> OFb (bf16, overlays O1)
    k_attn_mfma<<<512, 512, 0, stream>>>(Qb, XG, P1, biasF, O2);
    k_proj<1><<<400, 256, 0, stream>>>(O2, Wp2, p2b, OFb);
    k_unshuffle<<<320, 256, 0, stream>>>(OFb, out);
}